// Round 9
// baseline (517.229 us; speedup 1.0000x reference)
//
#include <hip/hip_runtime.h>
#include <stdint.h>

#define N_TOK 16384
#define DIM   1024
#define NEXP  8
#define FF    2048
#define CAP   2560
#define NSLOT (NEXP*CAP)   // 20480

using f32x4  = __attribute__((ext_vector_type(4))) float;
using bf16x8 = __attribute__((ext_vector_type(8))) short;

__device__ __forceinline__ unsigned short f2bf(float f){
  union { float f; unsigned u; } c; c.f = f;
  unsigned u = c.u + 0x7FFFu + ((c.u >> 16) & 1u);   // RNE
  return (unsigned short)(u >> 16);
}
__device__ __forceinline__ float bf2f(unsigned short h){
  union { unsigned u; float f; } c; c.u = ((unsigned)h) << 16; return c.f;
}

__device__ __forceinline__ void gld16(const unsigned short* g, unsigned short* l){
  __builtin_amdgcn_global_load_lds((__attribute__((address_space(1))) void*)(void*)g,
                                   (__attribute__((address_space(3))) void*)l,
                                   16, 0, 0);
}

#define HBAR __builtin_amdgcn_s_barrier()
#define LG0  asm volatile("s_waitcnt lgkmcnt(0)" ::: "memory")
#define SBAR0 __builtin_amdgcn_sched_barrier(0)

// ---------------- router: fp64 logits/softmax for ordering robustness ----------------
__global__ __launch_bounds__(256) void k_router(
    const float* __restrict__ x, const float* __restrict__ gate_w,
    float* __restrict__ probs, int* __restrict__ topidx, float* __restrict__ topw)
{
  __shared__ float gwT[NEXP][DIM];
  int tid = threadIdx.x;
  for (int i = tid; i < DIM*NEXP; i += 256) gwT[i & 7][i >> 3] = gate_w[i];
  __syncthreads();
  int wave = tid >> 6, lane = tid & 63;
  int t = blockIdx.x * 4 + wave;
  const float* xr = x + (size_t)t * DIM;
  double acc[NEXP];
  #pragma unroll
  for (int e = 0; e < NEXP; e++) acc[e] = 0.0;
  for (int j = 0; j < DIM/64; j++){
    double xv = (double)xr[lane + 64*j];
    #pragma unroll
    for (int e = 0; e < NEXP; e++) acc[e] += xv * (double)gwT[e][lane + 64*j];
  }
  #pragma unroll
  for (int off = 32; off >= 1; off >>= 1){
    #pragma unroll
    for (int e = 0; e < NEXP; e++) acc[e] += __shfl_xor(acc[e], off, 64);
  }
  if (lane == 0){
    double m = acc[0];
    #pragma unroll
    for (int e = 1; e < NEXP; e++) m = fmax(m, acc[e]);
    double p[NEXP], Z = 0.0;
    #pragma unroll
    for (int e = 0; e < NEXP; e++){ p[e] = exp(acc[e] - m); Z += p[e]; }
    double invZ = 1.0 / Z;
    #pragma unroll
    for (int e = 0; e < NEXP; e++){ p[e] *= invZ; probs[t*NEXP + e] = (float)p[e]; }
    int i0 = 0; double p0 = p[0];
    #pragma unroll
    for (int e = 1; e < NEXP; e++) if (p[e] > p0){ p0 = p[e]; i0 = e; }
    int i1 = (i0 == 0) ? 1 : 0; double p1 = p[i1];
    #pragma unroll
    for (int e = 0; e < NEXP; e++) if (e != i0 && p[e] > p1){ p1 = p[e]; i1 = e; }
    double s = p0 + p1;
    topidx[t*2+0] = i0; topidx[t*2+1] = i1;
    topw [t*2+0] = (float)(p0/s); topw[t*2+1] = (float)(p1/s);
  }
}

// ---------------- ordered capacity scan ----------------
__global__ __launch_bounds__(1024) void k_scan(
    const int* __restrict__ topidx,
    int* __restrict__ slot_token, int* __restrict__ tok_slots,
    int* __restrict__ counts_total)
{
  __shared__ int sc[1024][NEXP];
  const int t = threadIdx.x;
  const int base_i = t * 32;
  int ids[32];
  #pragma unroll
  for (int j = 0; j < 32; j++) ids[j] = topidx[base_i + j];
  int b[NEXP];
  #pragma unroll
  for (int e = 0; e < NEXP; e++) b[e] = 0;
  #pragma unroll
  for (int j = 0; j < 32; j++){
    #pragma unroll
    for (int e = 0; e < NEXP; e++) if (ids[j] == e) b[e]++;
  }
  #pragma unroll
  for (int e = 0; e < NEXP; e++) sc[t][e] = b[e];
  __syncthreads();
  for (int off = 1; off < 1024; off <<= 1){
    int tmp[NEXP];
    #pragma unroll
    for (int e = 0; e < NEXP; e++) tmp[e] = (t >= off) ? sc[t-off][e] : 0;
    __syncthreads();
    #pragma unroll
    for (int e = 0; e < NEXP; e++) sc[t][e] += tmp[e];
    __syncthreads();
  }
  int myb[NEXP];
  #pragma unroll
  for (int e = 0; e < NEXP; e++) myb[e] = sc[t][e] - b[e];
  if (t == 1023){
    #pragma unroll
    for (int e = 0; e < NEXP; e++) counts_total[e] = sc[1023][e];
  }
  #pragma unroll
  for (int j = 0; j < 32; j++){
    int slot = -1;
    #pragma unroll
    for (int e = 0; e < NEXP; e++){
      if (ids[j] == e){
        int r = myb[e]; myb[e] = r + 1;
        if (r < CAP){
          slot = e*CAP + r;
          slot_token[slot] = (base_i + j) >> 1;
        }
      }
    }
    tok_slots[base_i + j] = slot;
  }
}

// ---------------- vectorized transpose + cast, 64x64 f32 tile ----------------
template<int MODE>
__global__ __launch_bounds__(256) void k_tcv(
    const float* __restrict__ in, unsigned short* __restrict__ out,
    int R, int C, size_t estride)
{
  __shared__ float tt[64][65];
  const int e  = blockIdx.z;
  const float* ine = in + (size_t)e * R * C;
  unsigned short* oute = out + (size_t)e * estride;
  const int c0 = blockIdx.x * 64, r0 = blockIdx.y * 64;
  const int tid = threadIdx.x;
  #pragma unroll
  for (int i = 0; i < 4; i++){
    int idx = i*256 + tid;
    int row = idx >> 4, c4 = idx & 15;
    float4 v = *(const float4*)(ine + (size_t)(r0 + row)*C + c0 + c4*4);
    tt[c4*4+0][row] = v.x; tt[c4*4+1][row] = v.y;
    tt[c4*4+2][row] = v.z; tt[c4*4+3][row] = v.w;
  }
  __syncthreads();
  #pragma unroll
  for (int i = 0; i < 2; i++){
    int cl = i*32 + (tid >> 3);
    int rs = (tid & 7) * 8;
    int c  = c0 + cl;
    int orow = (MODE == 0) ? ((c>>4)*32 + (c&15))
             : (MODE == 1) ? ((c>>4)*32 + 16 + (c&15))
             : c;
    unsigned long long pk0 = 0, pk1 = 0;
    #pragma unroll
    for (int j = 0; j < 4; j++) pk0 |= (unsigned long long)f2bf(tt[cl][rs+j]) << (16*j);
    #pragma unroll
    for (int j = 0; j < 4; j++) pk1 |= (unsigned long long)f2bf(tt[cl][rs+4+j]) << (16*j);
    unsigned long long* dst = (unsigned long long*)(oute + (size_t)orow*R + r0 + rs);
    dst[0] = pk0; dst[1] = pk1;
  }
}

// ---------------- gather x rows into dispatched bf16 ----------------
__global__ __launch_bounds__(256) void k_gather(
    const float* __restrict__ x, const int* __restrict__ slot_token,
    unsigned short* __restrict__ disp)
{
  const int s = blockIdx.x;
  const int t = slot_token[s];
  const int tid = threadIdx.x;
  unsigned long long pk = 0ull;
  if (t >= 0){
    float4 v = *(const float4*)(x + (size_t)t*DIM + tid*4);
    pk =  (unsigned long long)f2bf(v.x)
       | ((unsigned long long)f2bf(v.y) << 16)
       | ((unsigned long long)f2bf(v.z) << 32)
       | ((unsigned long long)f2bf(v.w) << 48);
  }
  *(unsigned long long*)(disp + (size_t)s*DIM + tid*4) = pk;
}

// ================= shared GEMM pieces =================
__device__ __forceinline__ void stg(const unsigned short* gsrc, int ldg,
                                    unsigned short* Lh, int wave, int lane){
  const int sl = (lane & 3) ^ ((lane >> 3) & 3);   // inverse-swizzled source slot
  #pragma unroll
  for (int j = 0; j < 2; j++){
    int bi = wave*2 + j;
    gld16(gsrc + (size_t)(bi*16 + (lane >> 2))*ldg + sl*8, Lh + bi*512);
  }
}
__device__ __forceinline__ bf16x8 frd(const unsigned short* Lh, int r, int g){
  return *(const bf16x8*)(Lh + r*32 + (((g ^ ((r >> 1) & 3))) << 3));
}
template<int MG>
__device__ __forceinline__ void mm16(f32x4 (&acc)[8][4], const bf16x8 (&a)[4], const bf16x8 (&b)[4]){
  #pragma unroll
  for (int i = 0; i < 4; i++)
    #pragma unroll
    for (int n = 0; n < 4; n++)
      acc[MG*4+i][n] = __builtin_amdgcn_mfma_f32_16x16x32_bf16(a[i], b[n], acc[MG*4+i][n], 0, 0, 0);
}

#define HALF_STEP(RS, DOSTG, VMW, ASRC, BSRC)                                   \
  {                                                                             \
    unsigned short* LA = lds + (RS)*16384;                                      \
    unsigned short* LB = LA + 8192;                                             \
    unsigned short* NS = lds + (((RS)+3)&3)*16384;                              \
    bf16x8 a[4], b[4];                                                          \
    _Pragma("unroll")                                                           \
    for (int i = 0; i < 4; i++) a[i] = frd(LA, wr*128 + i*16 + l15, g);         \
    _Pragma("unroll")                                                           \
    for (int n = 0; n < 4; n++) b[n] = frd(LB, wc*64 + n*16 + l15, g);          \
    if (DOSTG) stg(ASRC, KDIM, NS, wave, lane);                                 \
    HBAR; LG0;                                                                  \
    __builtin_amdgcn_s_setprio(1);  mm16<0>(acc, a, b);                         \
    __builtin_amdgcn_s_setprio(0);                                              \
    HBAR;                                                                       \
    _Pragma("unroll")                                                           \
    for (int i = 0; i < 4; i++) a[i] = frd(LA, wr*128 + (4+i)*16 + l15, g);     \
    if (DOSTG) stg(BSRC, KDIM, NS + 8192, wave, lane);                          \
    HBAR; LG0;                                                                  \
    __builtin_amdgcn_s_setprio(1);  mm16<1>(acc, a, b);                         \
    __builtin_amdgcn_s_setprio(0);                                              \
    if ((VMW) == 4) { asm volatile("s_waitcnt vmcnt(4)" ::: "memory"); }        \
    else if ((VMW) == 0) { asm volatile("s_waitcnt vmcnt(0)" ::: "memory"); }   \
    HBAR;                                                                       \
  }

// ---------------- GEMM1: 256x256 ring-4, R4-proven schedule; silu epilogue ----------------
__global__ __launch_bounds__(512, 2) void k_gemm1(
    const unsigned short* __restrict__ A,
    const unsigned short* __restrict__ B,
    unsigned short* __restrict__ Out)
{
  constexpr int KDIM = DIM, NH = DIM/32;         // 32 halves
  __shared__ unsigned short lds[65536];          // 128 KiB = 4 half-slots
  const int id = blockIdx.x;
  const int e  = id & 7;                          // XCD-chunked: expert per XCD
  const int t  = id >> 3;
  const int mt = t % 10, nt = t / 10;
  const int m0 = mt*256, n0 = nt*256;
  const unsigned short* Ab = A + ((size_t)e*CAP  + m0) * KDIM;
  const unsigned short* Bb = B + ((size_t)e*2*FF + n0) * KDIM;
  const int tid = threadIdx.x, wave = tid >> 6, lane = tid & 63;
  const int wr = wave >> 2, wc = wave & 3;        // 2M x 4N waves
  const int g = lane >> 4, l15 = lane & 15;

  f32x4 acc[8][4];
  const f32x4 z4 = {0.f,0.f,0.f,0.f};
  #pragma unroll
  for (int i = 0; i < 8; i++)
    #pragma unroll
    for (int n = 0; n < 4; n++) acc[i][n] = z4;

  stg(Ab,      KDIM, lds + 0*16384,        wave, lane);
  stg(Bb,      KDIM, lds + 0*16384 + 8192, wave, lane);
  stg(Ab + 32, KDIM, lds + 1*16384,        wave, lane);
  stg(Bb + 32, KDIM, lds + 1*16384 + 8192, wave, lane);
  stg(Ab + 64, KDIM, lds + 2*16384,        wave, lane);
  stg(Bb + 64, KDIM, lds + 2*16384 + 8192, wave, lane);
  asm volatile("s_waitcnt vmcnt(4)" ::: "memory");
  HBAR;

  for (int h = 0; h + 8 <= NH; h += 4){
    HALF_STEP(0, true, -1, Ab + (size_t)(h+3)*32, Bb + (size_t)(h+3)*32);
    HALF_STEP(1, true,  4, Ab + (size_t)(h+4)*32, Bb + (size_t)(h+4)*32);
    HALF_STEP(2, true, -1, Ab + (size_t)(h+5)*32, Bb + (size_t)(h+5)*32);
    HALF_STEP(3, true,  4, Ab + (size_t)(h+6)*32, Bb + (size_t)(h+6)*32);
  }
  HALF_STEP(0, true, -1, Ab + (size_t)(NH-1)*32, Bb + (size_t)(NH-1)*32);
  HALF_STEP(1, false, 0, Ab, Bb);
  HALF_STEP(2, false, -1, Ab, Bb);
  HALF_STEP(3, false, -1, Ab, Bb);

  unsigned short* H = Out + ((size_t)e*CAP + m0 + wr*128) * (size_t)FF;
  const int hc0 = (n0 + wc*64) >> 1;
  #pragma unroll
  for (int mf = 0; mf < 8; mf++)
    #pragma unroll
    for (int q = 0; q < 4; q++){
      int r = mf*16 + g*4 + q;
      #pragma unroll
      for (int p = 0; p < 2; p++){
        float gg = acc[mf][2*p][q], uu = acc[mf][2*p+1][q];
        float h = gg / (1.f + __expf(-gg)) * uu;
        H[(size_t)r*FF + hc0 + p*16 + l15] = f2bf(h);
      }
    }
}

// ---------------- GEMM2: 256x128 ring-4, single-barrier counted-vmcnt (R6-proven loop) ----------------
// A = hidden [E*CAP][FF]; B = wdT [E][DIM][FF]; out = slot_out bf16 [E*CAP][DIM].
// 640 blocks = 2.5 rounds of ~40us -> kills the 1.25-round quantization of 256^2.
__global__ __launch_bounds__(512, 2) void k_gemm2t(
    const unsigned short* __restrict__ A,
    const unsigned short* __restrict__ B,
    unsigned short* __restrict__ Out)
{
  constexpr int KDIM = FF, NH = FF/32;            // 64 halves
  constexpr int SLOT = 12288;                     // shorts: A 8192 + B 4096 (24 KiB)
  __shared__ unsigned short lds[4*SLOT];          // 96 KiB
  const int id = blockIdx.x;
  const int e  = id & 7;
  const int t  = id >> 3;                          // 0..79
  const int mt = t % 10, nt = t / 10;              // 10 x 8
  const int m0 = mt*256, n0 = nt*128;
  const unsigned short* Ab = A + ((size_t)e*CAP + m0) * KDIM;
  const unsigned short* Bb = B + ((size_t)e*DIM + n0) * KDIM;
  const int tid = threadIdx.x, wave = tid >> 6, lane = tid & 63;
  const int wr = wave >> 2, wc = wave & 3;         // 2M x 4N waves, each 128x32 out
  const int g = lane >> 4, l15 = lane & 15;
  const int sl = (lane & 3) ^ ((lane >> 3) & 3);

  f32x4 acc[8][2];
  const f32x4 z4 = {0.f,0.f,0.f,0.f};
  #pragma unroll
  for (int i = 0; i < 8; i++)
    #pragma unroll
    for (int n = 0; n < 2; n++) acc[i][n] = z4;

  // stage half h into ring slot rs: A 2 gld + B 1 gld per thread (3 loads)
  auto stage = [&](int h, int rs){
    unsigned short* S = lds + rs*SLOT;
    const unsigned short* As = Ab + (size_t)h*32;
    const unsigned short* Bs = Bb + (size_t)h*32;
    #pragma unroll
    for (int j = 0; j < 2; j++){
      int bi = wave*2 + j;
      gld16(As + (size_t)(bi*16 + (lane >> 2))*KDIM + sl*8, S + bi*512);
    }
    gld16(Bs + (size_t)(wave*16 + (lane >> 2))*KDIM + sl*8, S + 8192 + wave*512);
  };

  stage(0,0); stage(1,1); stage(2,2);              // 9 loads/thread in flight

  for (int h = 0; h < NH; ++h){
    if (h < NH-2)      { asm volatile("s_waitcnt vmcnt(6)" ::: "memory"); }
    else if (h == NH-2){ asm volatile("s_waitcnt vmcnt(3)" ::: "memory"); }
    else               { asm volatile("s_waitcnt vmcnt(0)" ::: "memory"); }
    HBAR;                                   // publishes slot h; fences readers of slot h-1
    SBAR0;                                  // keep ds_reads below the barrier (rule #18)
    unsigned short* LA = lds + (h & 3)*SLOT;
    unsigned short* LB = LA + 8192;
    if (h + 3 < NH) stage(h+3, (h+3) & 3);
    bf16x8 a[4], a2[4], b[2];
    #pragma unroll
    for (int i = 0; i < 4; i++) a[i]  = frd(LA, wr*128 + i*16 + l15, g);
    #pragma unroll
    for (int n = 0; n < 2; n++) b[n]  = frd(LB, wc*32 + n*16 + l15, g);
    #pragma unroll
    for (int i = 0; i < 4; i++) a2[i] = frd(LA, wr*128 + (4+i)*16 + l15, g);
    __builtin_amdgcn_s_setprio(1);
    #pragma unroll
    for (int i = 0; i < 4; i++)
      #pragma unroll
      for (int n = 0; n < 2; n++)
        acc[i][n] = __builtin_amdgcn_mfma_f32_16x16x32_bf16(a[i], b[n], acc[i][n], 0, 0, 0);
    #pragma unroll
    for (int i = 0; i < 4; i++)
      #pragma unroll
      for (int n = 0; n < 2; n++)
        acc[4+i][n] = __builtin_amdgcn_mfma_f32_16x16x32_bf16(a2[i], b[n], acc[4+i][n], 0, 0, 0);
    __builtin_amdgcn_s_setprio(0);
  }

  unsigned short* O = Out + ((size_t)e*CAP + m0 + wr*128) * (size_t)DIM + n0 + wc*32;
  #pragma unroll
  for (int mf = 0; mf < 8; mf++)
    #pragma unroll
    for (int q = 0; q < 4; q++){
      int r = mf*16 + g*4 + q;
      #pragma unroll
      for (int n = 0; n < 2; n++)
        O[(size_t)r*DIM + n*16 + l15] = f2bf(acc[mf][n][q]);
    }
}

// ---------------- combine: 2 tokens per block, single partial ----------------
__global__ __launch_bounds__(256) void k_combine(
    const unsigned short* __restrict__ slot_out, const int* __restrict__ tok_slots,
    const float* __restrict__ topw, float* __restrict__ out)
{
  const int t = blockIdx.x*2 + (threadIdx.x >> 7);
  const int tid = threadIdx.x & 127;
  const int s0 = tok_slots[t*2+0], s1 = tok_slots[t*2+1];
  const float w0 = topw[t*2+0], w1 = topw[t*2+1];
  float r[8];
  #pragma unroll
  for (int j = 0; j < 8; j++) r[j] = 0.f;
  if (s0 >= 0){
    bf16x8 v = *(const bf16x8*)(slot_out + (size_t)s0*DIM + tid*8);
    #pragma unroll
    for (int j = 0; j < 8; j++) r[j] += w0 * bf2f((unsigned short)v[j]);
  }
  if (s1 >= 0){
    bf16x8 v = *(const bf16x8*)(slot_out + (size_t)s1*DIM + tid*8);
    #pragma unroll
    for (int j = 0; j < 8; j++) r[j] += w1 * bf2f((unsigned short)v[j]);
  }
  float4* o = (float4*)(out + (size_t)t*DIM + tid*8);
  o[0] = make_float4(r[0], r[1], r[2], r[3]);
  o[1] = make_float4(r[4], r[5], r[6], r[7]);
}

// ---------------- aux loss ----------------
__global__ __launch_bounds__(256) void k_aux(
    const float* __restrict__ probs, const int* __restrict__ counts_total,
    float* __restrict__ aux_out)
{
  const int tid = threadIdx.x;
  float pe[NEXP];
  #pragma unroll
  for (int e = 0; e < NEXP; e++) pe[e] = 0.f;
  for (int i = tid; i < N_TOK; i += 256){
    #pragma unroll
    for (int e = 0; e < NEXP; e++) pe[e] += probs[i*NEXP + e];
  }
  #pragma unroll
  for (int off = 32; off >= 1; off >>= 1){
    #pragma unroll
    for (int e = 0; e < NEXP; e++) pe[e] += __shfl_xor(pe[e], off, 64);
  }
  __shared__ float part[4][NEXP];
  const int wave = tid >> 6, lane = tid & 63;
  if (lane == 0){
    #pragma unroll
    for (int e = 0; e < NEXP; e++) part[wave][e] = pe[e];
  }
  __syncthreads();
  if (tid == 0){
    float aux = 0.f;
    for (int e = 0; e < NEXP; e++){
      float P = (part[0][e] + part[1][e] + part[2][e] + part[3][e]) / (float)N_TOK;
      float f = (float)counts_total[e] / ((float)(N_TOK*2) + 1e-9f);
      aux += f * P;
    }
    aux_out[0] = (float)NEXP * aux * 0.01f;
  }
}

extern "C" void kernel_launch(void* const* d_in, const int* in_sizes, int n_in,
                              void* d_out, int out_size, void* d_ws, size_t ws_size,
                              hipStream_t stream)
{
  const float* x      = (const float*)d_in[0];
  const float* gate_w = (const float*)d_in[1];
  const float* w_gate = (const float*)d_in[2];
  const float* w_up   = (const float*)d_in[3];
  const float* w_down = (const float*)d_in[4];
  float* out = (float*)d_out;

  uint8_t* ws = (uint8_t*)d_ws;
  float* probs        = (float*)ws;             ws += (size_t)N_TOK*NEXP*4;
  int*   topidx       = (int*)ws;               ws += (size_t)N_TOK*2*4;
  float* topw         = (float*)ws;             ws += (size_t)N_TOK*2*4;
  int*   slot_token   = (int*)ws;               ws += (size_t)NSLOT*4;
  int*   tok_slots    = (int*)ws;               ws += (size_t)N_TOK*2*4;
  int*   counts_total = (int*)ws;               ws += 256;
  unsigned short* disp   = (unsigned short*)ws; ws += (size_t)NSLOT*DIM*2;     // slot_out aliases after gemm1
  unsigned short* hidden = (unsigned short*)ws; ws += (size_t)NSLOT*FF*2;
  unsigned short* B1     = (unsigned short*)ws; ws += (size_t)NEXP*2*FF*DIM*2; // interleaved gate/up
  unsigned short* wdT    = (unsigned short*)ws; ws += (size_t)NEXP*DIM*FF*2;
  size_t need = (size_t)(ws - (uint8_t*)d_ws);
  if (ws_size < need) return;
  unsigned short* slot_out = disp;   // disp dead after gemm1

  hipMemsetAsync(slot_token, 0xFF, (size_t)NSLOT * sizeof(int), stream);

  k_router<<<N_TOK/4, 256, 0, stream>>>(x, gate_w, probs, topidx, topw);
  k_scan<<<1, 1024, 0, stream>>>(topidx, slot_token, tok_slots, counts_total);
  k_tcv<0><<<dim3(FF/64, DIM/64, NEXP), 256, 0, stream>>>(w_gate, B1, DIM, FF, (size_t)2*FF*DIM);
  k_tcv<1><<<dim3(FF/64, DIM/64, NEXP), 256, 0, stream>>>(w_up,   B1, DIM, FF, (size_t)2*FF*DIM);
  k_tcv<2><<<dim3(DIM/64, FF/64, NEXP), 256, 0, stream>>>(w_down, wdT, FF, DIM, (size_t)DIM*FF);
  k_gather<<<NSLOT, 256, 0, stream>>>(x, slot_token, disp);
  k_gemm1<<<1280, 512, 0, stream>>>(disp, B1, hidden);
  k_gemm2t<<<640, 512, 0, stream>>>(hidden, wdT, slot_out);
  k_combine<<<N_TOK/2, 256, 0, stream>>>(slot_out, tok_slots, topw, out);
  k_aux<<<1, 256, 0, stream>>>(probs, counts_total, out + (size_t)N_TOK*DIM);
}

// Round 10
// 483.359 us; speedup vs baseline: 1.0701x; 1.0701x over previous
//
#include <hip/hip_runtime.h>
#include <stdint.h>

#define N_TOK 16384
#define DIM   1024
#define NEXP  8
#define FF    2048
#define CAP   2560
#define NSLOT (NEXP*CAP)   // 20480

using f32x4  = __attribute__((ext_vector_type(4))) float;
using bf16x8 = __attribute__((ext_vector_type(8))) short;

__device__ __forceinline__ unsigned short f2bf(float f){
  union { float f; unsigned u; } c; c.f = f;
  unsigned u = c.u + 0x7FFFu + ((c.u >> 16) & 1u);   // RNE
  return (unsigned short)(u >> 16);
}
__device__ __forceinline__ float bf2f(unsigned short h){
  union { unsigned u; float f; } c; c.u = ((unsigned)h) << 16; return c.f;
}

__device__ __forceinline__ void gld16(const unsigned short* g, unsigned short* l){
  __builtin_amdgcn_global_load_lds((__attribute__((address_space(1))) void*)(void*)g,
                                   (__attribute__((address_space(3))) void*)l,
                                   16, 0, 0);
}

#define HBAR __builtin_amdgcn_s_barrier()
#define LG0  asm volatile("s_waitcnt lgkmcnt(0)" ::: "memory")
#define SBAR0 __builtin_amdgcn_sched_barrier(0)

// ---------------- router: fp64 logits/softmax for ordering robustness ----------------
__global__ __launch_bounds__(256) void k_router(
    const float* __restrict__ x, const float* __restrict__ gate_w,
    float* __restrict__ probs, int* __restrict__ topidx, float* __restrict__ topw)
{
  __shared__ float gwT[NEXP][DIM];
  int tid = threadIdx.x;
  for (int i = tid; i < DIM*NEXP; i += 256) gwT[i & 7][i >> 3] = gate_w[i];
  __syncthreads();
  int wave = tid >> 6, lane = tid & 63;
  int t = blockIdx.x * 4 + wave;
  const float* xr = x + (size_t)t * DIM;
  double acc[NEXP];
  #pragma unroll
  for (int e = 0; e < NEXP; e++) acc[e] = 0.0;
  for (int j = 0; j < DIM/64; j++){
    double xv = (double)xr[lane + 64*j];
    #pragma unroll
    for (int e = 0; e < NEXP; e++) acc[e] += xv * (double)gwT[e][lane + 64*j];
  }
  #pragma unroll
  for (int off = 32; off >= 1; off >>= 1){
    #pragma unroll
    for (int e = 0; e < NEXP; e++) acc[e] += __shfl_xor(acc[e], off, 64);
  }
  if (lane == 0){
    double m = acc[0];
    #pragma unroll
    for (int e = 1; e < NEXP; e++) m = fmax(m, acc[e]);
    double p[NEXP], Z = 0.0;
    #pragma unroll
    for (int e = 0; e < NEXP; e++){ p[e] = exp(acc[e] - m); Z += p[e]; }
    double invZ = 1.0 / Z;
    #pragma unroll
    for (int e = 0; e < NEXP; e++){ p[e] *= invZ; probs[t*NEXP + e] = (float)p[e]; }
    int i0 = 0; double p0 = p[0];
    #pragma unroll
    for (int e = 1; e < NEXP; e++) if (p[e] > p0){ p0 = p[e]; i0 = e; }
    int i1 = (i0 == 0) ? 1 : 0; double p1 = p[i1];
    #pragma unroll
    for (int e = 0; e < NEXP; e++) if (e != i0 && p[e] > p1){ p1 = p[e]; i1 = e; }
    double s = p0 + p1;
    topidx[t*2+0] = i0; topidx[t*2+1] = i1;
    topw [t*2+0] = (float)(p0/s); topw[t*2+1] = (float)(p1/s);
  }
}

// ---------------- ordered capacity scan + fused aux loss ----------------
__global__ __launch_bounds__(1024) void k_scan(
    const int* __restrict__ topidx, const float* __restrict__ probs,
    int* __restrict__ slot_token, int* __restrict__ tok_slots,
    float* __restrict__ aux_out)
{
  __shared__ int sc[1024][NEXP];
  const int t = threadIdx.x;
  const int base_i = t * 32;
  int ids[32];
  #pragma unroll
  for (int j = 0; j < 32; j++) ids[j] = topidx[base_i + j];
  int b[NEXP];
  #pragma unroll
  for (int e = 0; e < NEXP; e++) b[e] = 0;
  #pragma unroll
  for (int j = 0; j < 32; j++){
    #pragma unroll
    for (int e = 0; e < NEXP; e++) if (ids[j] == e) b[e]++;
  }
  #pragma unroll
  for (int e = 0; e < NEXP; e++) sc[t][e] = b[e];
  __syncthreads();
  for (int off = 1; off < 1024; off <<= 1){
    int tmp[NEXP];
    #pragma unroll
    for (int e = 0; e < NEXP; e++) tmp[e] = (t >= off) ? sc[t-off][e] : 0;
    __syncthreads();
    #pragma unroll
    for (int e = 0; e < NEXP; e++) sc[t][e] += tmp[e];
    __syncthreads();
  }
  int myb[NEXP];
  #pragma unroll
  for (int e = 0; e < NEXP; e++) myb[e] = sc[t][e] - b[e];
  int cnt[NEXP];
  #pragma unroll
  for (int e = 0; e < NEXP; e++) cnt[e] = sc[1023][e];   // totals (broadcast read)
  #pragma unroll
  for (int j = 0; j < 32; j++){
    int slot = -1;
    #pragma unroll
    for (int e = 0; e < NEXP; e++){
      if (ids[j] == e){
        int r = myb[e]; myb[e] = r + 1;
        if (r < CAP){
          slot = e*CAP + r;
          slot_token[slot] = (base_i + j) >> 1;
        }
      }
    }
    tok_slots[base_i + j] = slot;
  }
  // ---- fused aux: P_e = mean probs, f_e = cnt_e/(N*K), aux = E*sum(f*P)*0.01 ----
  __syncthreads();
  float pe[NEXP];
  #pragma unroll
  for (int e = 0; e < NEXP; e++) pe[e] = 0.f;
  for (int i = t; i < N_TOK; i += 1024){
    const float4* pr = (const float4*)(probs + i*NEXP);
    float4 v0 = pr[0], v1 = pr[1];
    pe[0] += v0.x; pe[1] += v0.y; pe[2] += v0.z; pe[3] += v0.w;
    pe[4] += v1.x; pe[5] += v1.y; pe[6] += v1.z; pe[7] += v1.w;
  }
  #pragma unroll
  for (int off = 32; off >= 1; off >>= 1){
    #pragma unroll
    for (int e = 0; e < NEXP; e++) pe[e] += __shfl_xor(pe[e], off, 64);
  }
  __syncthreads();
  float* scf = (float*)&sc[0][0];
  const int wv = t >> 6, ln = t & 63;
  if (ln == 0){
    #pragma unroll
    for (int e = 0; e < NEXP; e++) scf[wv*NEXP + e] = pe[e];
  }
  __syncthreads();
  if (t == 0){
    float aux = 0.f;
    #pragma unroll
    for (int e = 0; e < NEXP; e++){
      float P = 0.f;
      for (int w = 0; w < 16; w++) P += scf[w*NEXP + e];
      P /= (float)N_TOK;
      float f = (float)cnt[e] / ((float)(N_TOK*2) + 1e-9f);
      aux += f * P;
    }
    aux_out[0] = (float)NEXP * aux * 0.01f;
  }
}

// ---------------- merged transpose+cast: all three weights in one launch ----------------
// z = mode*8+e. mode0: w_gate->B1(gate rows); mode1: w_up->B1(up rows); mode2: w_down->wdT.
__global__ __launch_bounds__(256) void k_tcv_all(
    const float* __restrict__ wg, const float* __restrict__ wu, const float* __restrict__ wd,
    unsigned short* __restrict__ B1, unsigned short* __restrict__ wdT)
{
  __shared__ float tt[64][65];
  const int z = blockIdx.z, mode = z >> 3, e = z & 7;
  const float* in; unsigned short* out; int R, C, ct, rt;
  if (mode < 2){
    in  = (mode == 0 ? wg : wu) + (size_t)e * DIM * FF;
    out = B1 + (size_t)e * 2 * FF * DIM;
    R = DIM; C = FF; ct = blockIdx.x; rt = blockIdx.y;      // 32 x 16
  } else {
    in  = wd + (size_t)e * FF * DIM;
    out = wdT + (size_t)e * DIM * FF;
    R = FF; C = DIM; ct = blockIdx.y; rt = blockIdx.x;      // 16 x 32
  }
  const int c0 = ct * 64, r0 = rt * 64;
  const int tid = threadIdx.x;
  #pragma unroll
  for (int i = 0; i < 4; i++){
    int idx = i*256 + tid;
    int row = idx >> 4, c4 = idx & 15;
    float4 v = *(const float4*)(in + (size_t)(r0 + row)*C + c0 + c4*4);
    tt[c4*4+0][row] = v.x; tt[c4*4+1][row] = v.y;
    tt[c4*4+2][row] = v.z; tt[c4*4+3][row] = v.w;
  }
  __syncthreads();
  #pragma unroll
  for (int i = 0; i < 2; i++){
    int cl = i*32 + (tid >> 3);
    int rs = (tid & 7) * 8;
    int c  = c0 + cl;
    int orow = (mode == 0) ? ((c>>4)*32 + (c&15))
             : (mode == 1) ? ((c>>4)*32 + 16 + (c&15))
             : c;
    unsigned long long pk0 = 0, pk1 = 0;
    #pragma unroll
    for (int j = 0; j < 4; j++) pk0 |= (unsigned long long)f2bf(tt[cl][rs+j]) << (16*j);
    #pragma unroll
    for (int j = 0; j < 4; j++) pk1 |= (unsigned long long)f2bf(tt[cl][rs+4+j]) << (16*j);
    unsigned long long* dst = (unsigned long long*)(out + (size_t)orow*R + r0 + rs);
    dst[0] = pk0; dst[1] = pk1;
  }
}

// ---------------- gather x rows into dispatched bf16 ----------------
__global__ __launch_bounds__(256) void k_gather(
    const float* __restrict__ x, const int* __restrict__ slot_token,
    unsigned short* __restrict__ disp)
{
  const int s = blockIdx.x;
  const int t = slot_token[s];
  const int tid = threadIdx.x;
  unsigned long long pk = 0ull;
  if (t >= 0){
    float4 v = *(const float4*)(x + (size_t)t*DIM + tid*4);
    pk =  (unsigned long long)f2bf(v.x)
       | ((unsigned long long)f2bf(v.y) << 16)
       | ((unsigned long long)f2bf(v.z) << 32)
       | ((unsigned long long)f2bf(v.w) << 48);
  }
  *(unsigned long long*)(disp + (size_t)s*DIM + tid*4) = pk;
}

// ================= ring-4 256x256 GEMM, B-prefetch pipelined loop =================
__device__ __forceinline__ void stg(const unsigned short* gsrc, int ldg,
                                    unsigned short* Lh, int wave, int lane){
  const int sl = (lane & 3) ^ ((lane >> 3) & 3);   // inverse-swizzled source slot
  #pragma unroll
  for (int j = 0; j < 2; j++){
    int bi = wave*2 + j;
    gld16(gsrc + (size_t)(bi*16 + (lane >> 2))*ldg + sl*8, Lh + bi*512);
  }
}
__device__ __forceinline__ bf16x8 frd(const unsigned short* Lh, int r, int g){
  return *(const bf16x8*)(Lh + r*32 + (((g ^ ((r >> 1) & 3))) << 3));
}
template<int MG>
__device__ __forceinline__ void mm16(f32x4 (&acc)[8][4], const bf16x8 (&a)[4], const bf16x8 (&b)[4]){
  #pragma unroll
  for (int i = 0; i < 4; i++)
    #pragma unroll
    for (int n = 0; n < 4; n++)
      acc[MG*4+i][n] = __builtin_amdgcn_mfma_f32_16x16x32_bf16(a[i], b[n], acc[MG*4+i][n], 0, 0, 0);
}

// EPI 1: gemm1, silu epilogue -> hidden. EPI 2: gemm2 K-split -> partial ks.
// Per iter h: stage(h+3); read a(h),a2(h) + PREFETCH b(h+1); lgkm; MFMA with bheld;
// vmcnt(4) every iter (guarantees h+2 landed at next entry -> b-prefetch safe); barrier.
template<int KDIM, int LDG, int EPI>
__global__ __launch_bounds__(512, 2) void k_gemm8(
    const unsigned short* __restrict__ A,
    const unsigned short* __restrict__ B,
    unsigned short* __restrict__ Out0,
    unsigned short* __restrict__ Out1)
{
  constexpr int NH    = KDIM / 32;               // 32 halves
  constexpr int BROWS = (EPI == 1) ? 2*FF : DIM;
  constexpr int LDO   = (EPI == 1) ? FF : DIM;
  __shared__ unsigned short lds[65536];          // 128 KiB = 4 half-slots
  const int id = blockIdx.x;
  const int e  = id & 7;                          // XCD-chunked: expert per XCD
  int t  = id >> 3;
  int ks = 0;
  if (EPI == 2){ ks = t & 1; t >>= 1; }           // K-slice
  const int mt = t % 10, nt = t / 10;
  const int m0 = mt*256, n0 = nt*256;
  const unsigned short* Ab = A + ((size_t)e*CAP   + m0) * LDG + (size_t)ks*KDIM;
  const unsigned short* Bb = B + ((size_t)e*BROWS + n0) * LDG + (size_t)ks*KDIM;
  const int tid = threadIdx.x, wave = tid >> 6, lane = tid & 63;
  const int wr = wave >> 2, wc = wave & 3;        // 2M x 4N waves
  const int g = lane >> 4, l15 = lane & 15;

  f32x4 acc[8][4];
  const f32x4 z4 = {0.f,0.f,0.f,0.f};
  #pragma unroll
  for (int i = 0; i < 8; i++)
    #pragma unroll
    for (int n = 0; n < 4; n++) acc[i][n] = z4;

  // prologue: stage halves 0,1,2; vmcnt(4) -> halves 0,1 landed; read b(0)
  stg(Ab,      LDG, lds + 0*16384,        wave, lane);
  stg(Bb,      LDG, lds + 0*16384 + 8192, wave, lane);
  stg(Ab + 32, LDG, lds + 1*16384,        wave, lane);
  stg(Bb + 32, LDG, lds + 1*16384 + 8192, wave, lane);
  stg(Ab + 64, LDG, lds + 2*16384,        wave, lane);
  stg(Bb + 64, LDG, lds + 2*16384 + 8192, wave, lane);
  asm volatile("s_waitcnt vmcnt(4)" ::: "memory");
  HBAR;
  SBAR0;
  bf16x8 bh[4];
  #pragma unroll
  for (int n = 0; n < 4; n++) bh[n] = frd(lds + 8192, wc*64 + n*16 + l15, g);

  for (int h = 0; h < NH; ++h){
    unsigned short* LA = lds + (h & 3)*16384;
    if (h + 3 < NH){
      unsigned short* NS = lds + ((h+3) & 3)*16384;
      stg(Ab + (size_t)(h+3)*32, LDG, NS,        wave, lane);
      stg(Bb + (size_t)(h+3)*32, LDG, NS + 8192, wave, lane);
    }
    bf16x8 a[4], a2[4], bn[4];
    #pragma unroll
    for (int i = 0; i < 4; i++) a[i]  = frd(LA, wr*128 + i*16 + l15, g);
    #pragma unroll
    for (int i = 0; i < 4; i++) a2[i] = frd(LA, wr*128 + (4+i)*16 + l15, g);
    if (h + 1 < NH){
      unsigned short* NL = lds + ((h+1) & 3)*16384 + 8192;
      #pragma unroll
      for (int n = 0; n < 4; n++) bn[n] = frd(NL, wc*64 + n*16 + l15, g);
    }
    LG0; SBAR0;                              // rule #18: MFMA stays below the wait
    __builtin_amdgcn_s_setprio(1);
    mm16<0>(acc, a, bh);
    mm16<1>(acc, a2, bh);
    __builtin_amdgcn_s_setprio(0);
    if (h + 1 < NH){
      #pragma unroll
      for (int n = 0; n < 4; n++) bh[n] = bn[n];
    }
    if (h <= NH-4)      { asm volatile("s_waitcnt vmcnt(4)" ::: "memory"); }
    else if (h == NH-3) { asm volatile("s_waitcnt vmcnt(0)" ::: "memory"); }
    HBAR;
    SBAR0;
  }

  // ---- epilogue ----
  if (EPI == 1){
    unsigned short* H = Out0 + ((size_t)e*CAP + m0 + wr*128) * (size_t)LDO;
    const int hc0 = (n0 + wc*64) >> 1;
    #pragma unroll
    for (int mf = 0; mf < 8; mf++)
      #pragma unroll
      for (int q = 0; q < 4; q++){
        int r = mf*16 + g*4 + q;
        #pragma unroll
        for (int p = 0; p < 2; p++){
          float gg = acc[mf][2*p][q], uu = acc[mf][2*p+1][q];
          float h = gg / (1.f + __expf(-gg)) * uu;
          H[(size_t)r*LDO + hc0 + p*16 + l15] = f2bf(h);
        }
      }
  } else {
    unsigned short* P = (ks ? Out1 : Out0);
    unsigned short* O = P + ((size_t)e*CAP + m0 + wr*128) * (size_t)LDO + n0 + wc*64;
    #pragma unroll
    for (int mf = 0; mf < 8; mf++)
      #pragma unroll
      for (int q = 0; q < 4; q++){
        int r = mf*16 + g*4 + q;
        #pragma unroll
        for (int n = 0; n < 4; n++)
          O[(size_t)r*LDO + n*16 + l15] = f2bf(acc[mf][n][q]);
      }
  }
}

// ---------------- combine: out[t] = sum_k w_k * (P0[slot_k] + P1[slot_k]) ----------------
__global__ __launch_bounds__(256) void k_combine(
    const unsigned short* __restrict__ P0, const unsigned short* __restrict__ P1,
    const int* __restrict__ tok_slots, const float* __restrict__ topw,
    float* __restrict__ out)
{
  const int t = blockIdx.x*2 + (threadIdx.x >> 7);
  const int tid = threadIdx.x & 127;
  const int s0 = tok_slots[t*2+0], s1 = tok_slots[t*2+1];
  const float w0 = topw[t*2+0], w1 = topw[t*2+1];
  float r[8];
  #pragma unroll
  for (int j = 0; j < 8; j++) r[j] = 0.f;
  if (s0 >= 0){
    bf16x8 v0 = *(const bf16x8*)(P0 + (size_t)s0*DIM + tid*8);
    bf16x8 v1 = *(const bf16x8*)(P1 + (size_t)s0*DIM + tid*8);
    #pragma unroll
    for (int j = 0; j < 8; j++)
      r[j] += w0 * (bf2f((unsigned short)v0[j]) + bf2f((unsigned short)v1[j]));
  }
  if (s1 >= 0){
    bf16x8 v0 = *(const bf16x8*)(P0 + (size_t)s1*DIM + tid*8);
    bf16x8 v1 = *(const bf16x8*)(P1 + (size_t)s1*DIM + tid*8);
    #pragma unroll
    for (int j = 0; j < 8; j++)
      r[j] += w1 * (bf2f((unsigned short)v0[j]) + bf2f((unsigned short)v1[j]));
  }
  float4* o = (float4*)(out + (size_t)t*DIM + tid*8);
  o[0] = make_float4(r[0], r[1], r[2], r[3]);
  o[1] = make_float4(r[4], r[5], r[6], r[7]);
}

extern "C" void kernel_launch(void* const* d_in, const int* in_sizes, int n_in,
                              void* d_out, int out_size, void* d_ws, size_t ws_size,
                              hipStream_t stream)
{
  const float* x      = (const float*)d_in[0];
  const float* gate_w = (const float*)d_in[1];
  const float* w_gate = (const float*)d_in[2];
  const float* w_up   = (const float*)d_in[3];
  const float* w_down = (const float*)d_in[4];
  float* out = (float*)d_out;

  uint8_t* ws = (uint8_t*)d_ws;
  float* probs        = (float*)ws;             ws += (size_t)N_TOK*NEXP*4;
  int*   topidx       = (int*)ws;               ws += (size_t)N_TOK*2*4;
  float* topw         = (float*)ws;             ws += (size_t)N_TOK*2*4;
  int*   slot_token   = (int*)ws;               ws += (size_t)NSLOT*4;
  int*   tok_slots    = (int*)ws;               ws += (size_t)N_TOK*2*4;
  int*   counts_total = (int*)ws;               ws += 256;  (void)counts_total;
  unsigned short* disp   = (unsigned short*)ws; ws += (size_t)NSLOT*DIM*2;     // P0 aliases after gemm1
  unsigned short* hidden = (unsigned short*)ws; ws += (size_t)NSLOT*FF*2;
  unsigned short* B1     = (unsigned short*)ws; ws += (size_t)NEXP*2*FF*DIM*2; // P1 aliases after gemm1
  unsigned short* wdT    = (unsigned short*)ws; ws += (size_t)NEXP*DIM*FF*2;
  size_t need = (size_t)(ws - (uint8_t*)d_ws);
  if (ws_size < need) return;
  unsigned short* P0 = disp;   // dead after gemm1 consumes it
  unsigned short* P1 = B1;     // dead after gemm1 consumes it (67 MB >= 42 MB)

  hipMemsetAsync(slot_token, 0xFF, (size_t)NSLOT * sizeof(int), stream);

  k_router<<<N_TOK/4, 256, 0, stream>>>(x, gate_w, probs, topidx, topw);
  k_scan<<<1, 1024, 0, stream>>>(topidx, probs, slot_token, tok_slots,
                                 out + (size_t)N_TOK*DIM);
  k_tcv_all<<<dim3(32, 16, 24), 256, 0, stream>>>(w_gate, w_up, w_down, B1, wdT);
  k_gather<<<NSLOT, 256, 0, stream>>>(x, slot_token, disp);
  // gemm1: 1280 blocks = 5 exact rounds
  k_gemm8<DIM, DIM, 1><<<1280, 512, 0, stream>>>(disp, B1, hidden, nullptr);
  // gemm2: K-split 2, each slice K=1024 (same loop); 640 blocks
  k_gemm8<DIM, FF, 2><<<640, 512, 0, stream>>>(hidden, wdT, P0, P1);
  k_combine<<<N_TOK/2, 256, 0, stream>>>(P0, P1, tok_slots, topw, out);
}